// Round 1
// baseline (12527.612 us; speedup 1.0000x reference)
//
#include <hip/hip_runtime.h>
#include <cmath>

#define KS 3
#define DGN 4
#define CHN 256
#define CGN 64
#define KK 9
#define CK 2304   // CHN*KK
#define TP 8

// Kernel 1: fused loc(1ch)+shape(2ch) 3x3 conv, pad 1, + sigmoid / exp transforms.
__global__ void __launch_bounds__(256) locshape_kernel(
    const float* __restrict__ f,        // [N,256,H,W]
    const float* __restrict__ loc_w,    // [1,256,3,3]
    const float* __restrict__ loc_b,    // [1]
    const float* __restrict__ shape_w,  // [2,256,3,3]
    const float* __restrict__ shape_b,  // [2]
    float* __restrict__ loc_out,        // [N,1,H,W]
    float* __restrict__ sh_out,         // [N,2,H,W]
    float* __restrict__ ref_out,        // [N,2,H,W]
    int N, int H, int W, float sigstride)
{
    __shared__ float wl[CK], ws0[CK], ws1[CK];
    for (int i = threadIdx.x; i < CK; i += 256) {
        wl[i]  = loc_w[i];
        ws0[i] = shape_w[i];
        ws1[i] = shape_w[CK + i];
    }
    __syncthreads();
    int p = blockIdx.x * 256 + threadIdx.x;
    int total = N * H * W;
    if (p >= total) return;
    int w = p % W, h = (p / W) % H, n = p / (W * H);
    long HW = (long)H * W;
    float a0 = 0.f, a1 = 0.f, a2 = 0.f;
    const float* fb = f + (long)n * CHN * HW;
    for (int c = 0; c < CHN; ++c) {
        const float* fc = fb + c * HW;
        int cb = c * KK;
        #pragma unroll
        for (int ky = 0; ky < KS; ++ky) {
            int y = h - 1 + ky;
            if ((unsigned)y >= (unsigned)H) continue;
            #pragma unroll
            for (int kx = 0; kx < KS; ++kx) {
                int x = w - 1 + kx;
                if ((unsigned)x >= (unsigned)W) continue;
                float v = fc[(long)y * W + x];
                int ki = cb + ky * KS + kx;
                a0 = fmaf(v, wl[ki], a0);
                a1 = fmaf(v, ws0[ki], a1);
                a2 = fmaf(v, ws1[ki], a2);
            }
        }
    }
    a0 += loc_b[0];
    a1 += shape_b[0];
    a2 += shape_b[1];
    long sp = (long)h * W + w;
    loc_out[n * HW + sp] = 1.f / (1.f + expf(-a0));
    sh_out[(n * 2 + 0) * HW + sp] = a1;
    sh_out[(n * 2 + 1) * HW + sp] = a2;
    ref_out[(n * 2 + 0) * HW + sp] = sigstride * expf(a1);
    ref_out[(n * 2 + 1) * HW + sp] = sigstride * expf(a2);
}

// Kernel 2: deformable conv v1 (DG=4, 3x3, pad 1) + ReLU.
// Offsets recomputed on the fly from sh (1x1 conv with offset_w).
// Block: 256 threads, TP=8 pixels. Stage im2col val[8][2304] in LDS,
// then each thread computes 8 consecutive output channels for 1 pixel.
__global__ void __launch_bounds__(256) deform_kernel(
    const float* __restrict__ f,     // [N,256,H,W]
    const float* __restrict__ sh,    // [N,2,H,W]
    const float* __restrict__ offw,  // [72,2,1,1]
    const float* __restrict__ adw,   // [256,256,3,3] -> [256][2304]
    float* __restrict__ out,         // [N,256,H,W]
    int N, int H, int W)
{
    __shared__ float val[TP][CK];
    int tid = threadIdx.x;
    int pix0 = blockIdx.x * TP;
    int total = N * H * W;
    long HW = (long)H * W;

    // Stage 1: offsets + bilinear sampling into LDS (im2col layout j = ch*9 + k)
    for (int t = tid; t < TP * DGN * KK; t += 256) {
        int p  = t / (DGN * KK);
        int gk = t % (DGN * KK);      // g*9 + k
        int g = gk / KK, k = gk % KK;
        int pix = pix0 + p;
        int vbase = g * CGN * KK + k;
        if (pix >= total) {
            for (int c = 0; c < CGN; ++c) val[p][vbase + c * KK] = 0.f;
            continue;
        }
        int w = pix % W, h = (pix / W) % H, n = pix / (W * H);
        float s0 = sh[(n * 2 + 0) * HW + (long)h * W + w];
        float s1 = sh[(n * 2 + 1) * HW + (long)h * W + w];
        // offset channels: dy -> (g*9+k)*2+0, dx -> (g*9+k)*2+1 ; offw[oc][c]
        int ocy = gk * 2;
        float dy = offw[ocy * 2 + 0] * s0 + offw[ocy * 2 + 1] * s1;
        float dx = offw[ocy * 2 + 2] * s0 + offw[ocy * 2 + 3] * s1;
        int ky = k / KS, kx = k % KS;
        float py = (float)(h - 1 + ky) + dy;
        float px = (float)(w - 1 + kx) + dx;
        float fy = floorf(py), fx = floorf(px);
        float ly = py - fy, lx = px - fx;
        int y0 = (int)fy, x0 = (int)fx;
        int y1 = y0 + 1, x1 = x0 + 1;
        float w00 = (1.f - ly) * (1.f - lx);
        float w01 = (1.f - ly) * lx;
        float w10 = ly * (1.f - lx);
        float w11 = ly * lx;
        float m00 = ((unsigned)y0 < (unsigned)H && (unsigned)x0 < (unsigned)W) ? w00 : 0.f;
        float m01 = ((unsigned)y0 < (unsigned)H && (unsigned)x1 < (unsigned)W) ? w01 : 0.f;
        float m10 = ((unsigned)y1 < (unsigned)H && (unsigned)x0 < (unsigned)W) ? w10 : 0.f;
        float m11 = ((unsigned)y1 < (unsigned)H && (unsigned)x1 < (unsigned)W) ? w11 : 0.f;
        int cy0 = min(max(y0, 0), H - 1), cy1 = min(max(y1, 0), H - 1);
        int cx0 = min(max(x0, 0), W - 1), cx1 = min(max(x1, 0), W - 1);
        long i00 = (long)cy0 * W + cx0;
        long i01 = (long)cy0 * W + cx1;
        long i10 = (long)cy1 * W + cx0;
        long i11 = (long)cy1 * W + cx1;
        const float* fb = f + ((long)n * CHN + g * CGN) * HW;
        for (int c = 0; c < CGN; ++c) {
            const float* fc = fb + c * HW;
            float v = fmaf(m00, fc[i00],
                      fmaf(m01, fc[i01],
                      fmaf(m10, fc[i10], m11 * fc[i11])));
            val[p][vbase + c * KK] = v;
        }
    }
    __syncthreads();

    // Stage 2: out[o, pixel] = sum_j adw[o][j] * val[p][j]
    // thread -> (8 consecutive o, 1 pixel): ob = (tid&31)*8, p = tid>>5
    int ob = (tid & 31) * 8;
    int p  = tid >> 5;
    int pix = pix0 + p;
    float acc[8];
    #pragma unroll
    for (int i = 0; i < 8; ++i) acc[i] = 0.f;
    const float* wp = adw + (long)ob * CK;
    for (int j = 0; j < CK; j += 4) {
        float4 vv = *(const float4*)&val[p][j];
        #pragma unroll
        for (int i = 0; i < 8; ++i) {
            float4 w4 = *(const float4*)(wp + (long)i * CK + j);
            acc[i] = fmaf(w4.x, vv.x, acc[i]);
            acc[i] = fmaf(w4.y, vv.y, acc[i]);
            acc[i] = fmaf(w4.z, vv.z, acc[i]);
            acc[i] = fmaf(w4.w, vv.w, acc[i]);
        }
    }
    if (pix < total) {
        int w = pix % W, h = (pix / W) % H, n = pix / (W * H);
        long sp = (long)h * W + w;
        #pragma unroll
        for (int i = 0; i < 8; ++i) {
            float r = acc[i];
            out[((long)n * CHN + ob + i) * HW + sp] = r > 0.f ? r : 0.f;
        }
    }
}

extern "C" void kernel_launch(void* const* d_in, const int* in_sizes, int n_in,
                              void* d_out, int out_size, void* d_ws, size_t ws_size,
                              hipStream_t stream)
{
    const int N = 2;
    const int Hs[4] = {100, 50, 25, 13};
    const int Ws[4] = {152, 76, 38, 19};
    const float sigstr[4] = {64.f, 128.f, 256.f, 512.f};  // SIGMA * stride

    const float* feats[4] = {(const float*)d_in[0], (const float*)d_in[1],
                             (const float*)d_in[2], (const float*)d_in[3]};
    const float* loc_w   = (const float*)d_in[4];
    const float* loc_b   = (const float*)d_in[5];
    const float* shape_w = (const float*)d_in[6];
    const float* shape_b = (const float*)d_in[7];
    const float* offset_w= (const float*)d_in[8];
    const float* adapt_w = (const float*)d_in[9];
    float* out = (float*)d_out;

    long hw[4], loc_off[4], sh_off[4], ref_off[4], ad_off[4];
    long off = 0;
    for (int l = 0; l < 4; ++l) hw[l] = (long)Hs[l] * Ws[l];
    for (int l = 0; l < 4; ++l) { loc_off[l] = off; off += (long)N * hw[l]; }
    for (int l = 0; l < 4; ++l) { sh_off[l]  = off; off += (long)N * 2 * hw[l]; }
    for (int l = 0; l < 4; ++l) { ref_off[l] = off; off += (long)N * 2 * hw[l]; }
    for (int l = 0; l < 4; ++l) { ad_off[l]  = off; off += (long)N * 256 * hw[l]; }

    for (int l = 0; l < 4; ++l) {
        int H = Hs[l], W = Ws[l];
        int total = N * H * W;
        int g1 = (total + 255) / 256;
        locshape_kernel<<<g1, 256, 0, stream>>>(
            feats[l], loc_w, loc_b, shape_w, shape_b,
            out + loc_off[l], out + sh_off[l], out + ref_off[l],
            N, H, W, sigstr[l]);
        int g2 = (total + TP - 1) / TP;
        deform_kernel<<<g2, 256, 0, stream>>>(
            feats[l], out + sh_off[l], offset_w, adapt_w,
            out + ad_off[l], N, H, W);
    }
}

// Round 2
// 856.839 us; speedup vs baseline: 14.6207x; 14.6207x over previous
//
#include <hip/hip_runtime.h>
#include <hip/hip_bf16.h>
#include <cmath>

#define KS 3
#define DGN 4
#define CHN 256
#define CGN 64
#define KK 9
#define CK 2304         // CHN*KK
#define TP 16           // pixels per deform block
#define PADK 2312       // CK + 8 bf16 pad

typedef short bf16x8 __attribute__((ext_vector_type(8)));
typedef float f32x4 __attribute__((ext_vector_type(4)));

static __device__ __forceinline__ short f2bf(float v) {
    __hip_bfloat16 h = __float2bfloat16(v);
    return *reinterpret_cast<short*>(&h);
}

// Kernel 0: convert adapt_w [256][c*9+k] fp32 -> bf16 [256][k*256+c] in ws
__global__ void __launch_bounds__(256) wconv_kernel(
    const float* __restrict__ adw, short* __restrict__ wbf)
{
    int i = blockIdx.x * 256 + threadIdx.x;
    if (i >= CHN * CK) return;
    int o = i / CK, j = i % CK;      // j = k*256 + c
    int k = j >> 8, c = j & 255;
    wbf[i] = f2bf(adw[o * CK + c * KK + k]);
}

// Kernel 1: fused loc(1)+shape(2) 3x3 conv pad1 + sigmoid/exp.
// 256 thr = 32 px x 8 channel-groups(32ch); LDS reduce.
__global__ void __launch_bounds__(256) locshape_kernel(
    const float* __restrict__ f,
    const float* __restrict__ loc_w, const float* __restrict__ loc_b,
    const float* __restrict__ shape_w, const float* __restrict__ shape_b,
    float* __restrict__ loc_out, float* __restrict__ sh_out,
    float* __restrict__ ref_out,
    int N, int H, int W, float sigstride)
{
    __shared__ float wsm[3][CK];
    __shared__ float red[3][256];
    int tid = threadIdx.x;
    for (int i = tid; i < CK; i += 256) {
        wsm[0][i] = loc_w[i];
        wsm[1][i] = shape_w[i];
        wsm[2][i] = shape_w[CK + i];
    }
    __syncthreads();

    int px = tid & 31, cg = tid >> 5;
    int pix = blockIdx.x * 32 + px;
    int total = N * H * W;
    long HW = (long)H * W;
    float a0 = 0.f, a1 = 0.f, a2 = 0.f;
    if (pix < total) {
        int w = pix % W, h = (pix / W) % H, n = pix / (W * H);
        int idx9[9]; float msk9[9];
        #pragma unroll
        for (int ky = 0; ky < 3; ++ky)
            #pragma unroll
            for (int kx = 0; kx < 3; ++kx) {
                int y = h - 1 + ky, x = w - 1 + kx;
                bool v = ((unsigned)y < (unsigned)H) && ((unsigned)x < (unsigned)W);
                idx9[ky * 3 + kx] = v ? (y * W + x) : 0;
                msk9[ky * 3 + kx] = v ? 1.f : 0.f;
            }
        const float* fb = f + ((long)n * CHN + cg * 32) * HW;
        for (int c = 0; c < 32; ++c) {
            const float* fc = fb + (long)c * HW;
            int wb = (cg * 32 + c) * KK;
            #pragma unroll
            for (int kk = 0; kk < 9; ++kk) {
                float v = msk9[kk] * fc[idx9[kk]];
                a0 = fmaf(v, wsm[0][wb + kk], a0);
                a1 = fmaf(v, wsm[1][wb + kk], a1);
                a2 = fmaf(v, wsm[2][wb + kk], a2);
            }
        }
    }
    red[0][tid] = a0; red[1][tid] = a1; red[2][tid] = a2;
    __syncthreads();
    if (tid < 32) {
        int pixo = blockIdx.x * 32 + tid;
        if (pixo < total) {
            float s0 = 0.f, s1 = 0.f, s2 = 0.f;
            #pragma unroll
            for (int g = 0; g < 8; ++g) {
                s0 += red[0][g * 32 + tid];
                s1 += red[1][g * 32 + tid];
                s2 += red[2][g * 32 + tid];
            }
            s0 += loc_b[0]; s1 += shape_b[0]; s2 += shape_b[1];
            int w = pixo % W, h = (pixo / W) % H, n = pixo / (W * H);
            long sp = (long)h * W + w;
            loc_out[n * HW + sp] = 1.f / (1.f + expf(-s0));
            sh_out[(n * 2 + 0) * HW + sp] = s1;
            sh_out[(n * 2 + 1) * HW + sp] = s2;
            ref_out[(n * 2 + 0) * HW + sp] = sigstride * expf(s1);
            ref_out[(n * 2 + 1) * HW + sp] = sigstride * expf(s2);
        }
    }
}

// Kernel 2: deformable conv v1 + ReLU via MFMA.
// Stage 1: bilinear im2col -> LDS bf16 val[16px][2312], j = k*256+c order.
// Stage 2: 4 waves x (64 out-ch x 16 px), mfma_f32_16x16x32_bf16,
//          A-frags from bf16 weights in ws (global/L2), B-frags ds_read_b128.
__global__ void __launch_bounds__(256) deform_kernel(
    const float* __restrict__ f,
    const float* __restrict__ sh,
    const float* __restrict__ offw,
    const short* __restrict__ wbf,   // [256][2304] bf16, j = k*256+c
    float* __restrict__ out,
    int N, int H, int W)
{
    __shared__ short val[TP][PADK];
    int tid = threadIdx.x;
    int pix0 = blockIdx.x * TP;
    int total = N * H * W;
    long HW = (long)H * W;

    // ---- Stage 1: im2col (bilinear + offsets recomputed from sh) ----
    for (int t = tid; t < TP * DGN * KK; t += 256) {
        int p = t / (DGN * KK);
        int gk = t % (DGN * KK);
        int g = gk / KK, k = gk % KK;
        int pix = pix0 + p;
        int jbase = k * 256 + g * CGN;
        if (pix >= total) {
            bf16x8 z = {0, 0, 0, 0, 0, 0, 0, 0};
            #pragma unroll
            for (int cb = 0; cb < 8; ++cb)
                *(bf16x8*)&val[p][jbase + cb * 8] = z;
            continue;
        }
        int w = pix % W, h = (pix / W) % H, n = pix / (W * H);
        float s0 = sh[(n * 2 + 0) * HW + (long)h * W + w];
        float s1 = sh[(n * 2 + 1) * HW + (long)h * W + w];
        int ocy = gk * 2;
        float dy = offw[ocy * 2 + 0] * s0 + offw[ocy * 2 + 1] * s1;
        float dx = offw[ocy * 2 + 2] * s0 + offw[ocy * 2 + 3] * s1;
        int ky = k / KS, kx = k % KS;
        float py = (float)(h - 1 + ky) + dy;
        float px = (float)(w - 1 + kx) + dx;
        float fy = floorf(py), fx = floorf(px);
        float ly = py - fy, lx = px - fx;
        int y0 = (int)fy, x0 = (int)fx;
        int y1 = y0 + 1, x1 = x0 + 1;
        float w00 = (1.f - ly) * (1.f - lx);
        float w01 = (1.f - ly) * lx;
        float w10 = ly * (1.f - lx);
        float w11 = ly * lx;
        float m00 = ((unsigned)y0 < (unsigned)H && (unsigned)x0 < (unsigned)W) ? w00 : 0.f;
        float m01 = ((unsigned)y0 < (unsigned)H && (unsigned)x1 < (unsigned)W) ? w01 : 0.f;
        float m10 = ((unsigned)y1 < (unsigned)H && (unsigned)x0 < (unsigned)W) ? w10 : 0.f;
        float m11 = ((unsigned)y1 < (unsigned)H && (unsigned)x1 < (unsigned)W) ? w11 : 0.f;
        int cy0 = min(max(y0, 0), H - 1), cy1 = min(max(y1, 0), H - 1);
        int cx0 = min(max(x0, 0), W - 1), cx1 = min(max(x1, 0), W - 1);
        long i00 = (long)cy0 * W + cx0;
        long i01 = (long)cy0 * W + cx1;
        long i10 = (long)cy1 * W + cx0;
        long i11 = (long)cy1 * W + cx1;
        const float* fb = f + ((long)n * CHN + g * CGN) * HW;
        #pragma unroll 1
        for (int cb = 0; cb < 8; ++cb) {
            short pk[8];
            #pragma unroll
            for (int u = 0; u < 8; ++u) {
                const float* fc = fb + (long)(cb * 8 + u) * HW;
                float v = fmaf(m00, fc[i00],
                          fmaf(m01, fc[i01],
                          fmaf(m10, fc[i10], m11 * fc[i11])));
                pk[u] = f2bf(v);
            }
            *(bf16x8*)&val[p][jbase + cb * 8] = *(bf16x8*)pk;
        }
    }
    __syncthreads();

    // ---- Stage 2: MFMA GEMM ----
    int wv = tid >> 6, lane = tid & 63;
    int nn = lane & 15, c8 = lane >> 4;
    f32x4 acc[4];
    #pragma unroll
    for (int mt = 0; mt < 4; ++mt) acc[mt] = (f32x4){0.f, 0.f, 0.f, 0.f};

    const short* wp0 = wbf + (size_t)(wv * 64 + nn) * CK + c8 * 8;
    const short* vrow = &val[nn][c8 * 8];

    #pragma unroll 2
    for (int k0 = 0; k0 < CK; k0 += 32) {
        bf16x8 bfr = *(const bf16x8*)(vrow + k0);
        #pragma unroll
        for (int mt = 0; mt < 4; ++mt) {
            bf16x8 afr = *(const bf16x8*)(wp0 + (size_t)mt * 16 * CK + k0);
            acc[mt] = __builtin_amdgcn_mfma_f32_16x16x32_bf16(afr, bfr, acc[mt], 0, 0, 0);
        }
    }

    int pix = pix0 + nn;
    if (pix < total) {
        int w = pix % W, h = (pix / W) % H, n = pix / (W * H);
        long sp = (long)h * W + w;
        #pragma unroll
        for (int mt = 0; mt < 4; ++mt) {
            #pragma unroll
            for (int r = 0; r < 4; ++r) {
                int oc = wv * 64 + mt * 16 + c8 * 4 + r;
                float v = acc[mt][r];
                out[((long)n * CHN + oc) * HW + sp] = v > 0.f ? v : 0.f;
            }
        }
    }
}

extern "C" void kernel_launch(void* const* d_in, const int* in_sizes, int n_in,
                              void* d_out, int out_size, void* d_ws, size_t ws_size,
                              hipStream_t stream)
{
    const int N = 2;
    const int Hs[4] = {100, 50, 25, 13};
    const int Ws[4] = {152, 76, 38, 19};
    const float sigstr[4] = {64.f, 128.f, 256.f, 512.f};

    const float* feats[4] = {(const float*)d_in[0], (const float*)d_in[1],
                             (const float*)d_in[2], (const float*)d_in[3]};
    const float* loc_w   = (const float*)d_in[4];
    const float* loc_b   = (const float*)d_in[5];
    const float* shape_w = (const float*)d_in[6];
    const float* shape_b = (const float*)d_in[7];
    const float* offset_w= (const float*)d_in[8];
    const float* adapt_w = (const float*)d_in[9];
    float* out = (float*)d_out;
    short* wbf = (short*)d_ws;   // 256*2304 bf16 = 1.18 MB

    long hw[4], loc_off[4], sh_off[4], ref_off[4], ad_off[4];
    long off = 0;
    for (int l = 0; l < 4; ++l) hw[l] = (long)Hs[l] * Ws[l];
    for (int l = 0; l < 4; ++l) { loc_off[l] = off; off += (long)N * hw[l]; }
    for (int l = 0; l < 4; ++l) { sh_off[l]  = off; off += (long)N * 2 * hw[l]; }
    for (int l = 0; l < 4; ++l) { ref_off[l] = off; off += (long)N * 2 * hw[l]; }
    for (int l = 0; l < 4; ++l) { ad_off[l]  = off; off += (long)N * 256 * hw[l]; }

    wconv_kernel<<<(CHN * CK + 255) / 256, 256, 0, stream>>>(adapt_w, wbf);

    for (int l = 0; l < 4; ++l) {
        int H = Hs[l], W = Ws[l];
        int total = N * H * W;
        int g1 = (total + 31) / 32;
        locshape_kernel<<<g1, 256, 0, stream>>>(
            feats[l], loc_w, loc_b, shape_w, shape_b,
            out + loc_off[l], out + sh_off[l], out + ref_off[l],
            N, H, W, sigstr[l]);
        int g2 = (total + TP - 1) / TP;
        deform_kernel<<<g2, 256, 0, stream>>>(
            feats[l], out + sh_off[l], offset_w, wbf,
            out + ad_off[l], N, H, W);
    }
}

// Round 3
// 417.150 us; speedup vs baseline: 30.0314x; 2.0540x over previous
//
#include <hip/hip_runtime.h>
#include <hip/hip_bf16.h>
#include <cmath>

typedef short s16x4  __attribute__((ext_vector_type(4)));
typedef short bf16x8 __attribute__((ext_vector_type(8)));
typedef float f32x4  __attribute__((ext_vector_type(4)));
typedef _Float16 h16x4 __attribute__((ext_vector_type(4)));

#define CK 2304
#define PADK 2320      // val row stride (shorts)
#define TP 32          // pixels per fused block

// per-level constants
__device__ __constant__ int   cH[4]   = {100, 50, 25, 13};
__device__ __constant__ int   cW[4]   = {152, 76, 38, 19};
__device__ __constant__ int   cHW[4]  = {15200, 3800, 950, 247};
__device__ __constant__ int   cFTO[4] = {0, 7782400, 9728000, 10214400};   // ft elem offsets
__device__ __constant__ int   cLOC[4] = {0, 30400, 38000, 39900};
__device__ __constant__ int   cSH[4]  = {40394, 101194, 116394, 120194};
__device__ __constant__ int   cREF[4] = {121182, 181982, 197182, 200982};
__device__ __constant__ int   cAD[4]  = {201970, 7984370, 9929970, 10416370};
__device__ __constant__ float cSS[4]  = {64.f, 128.f, 256.f, 512.f};
// fused grid: blocks/level {950,238,60,16} cum {950,1188,1248,1264}
// transpose grid: nbhw {238,60,15,4}, blocks/level {1904,480,120,32} cum {1904,2384,2504,2536}

static __device__ __forceinline__ short f2bf(float v) {
    __hip_bfloat16 h = __float2bfloat16(v);
    return *reinterpret_cast<short*>(&h);
}

// ---------------- Kernel 0: weight prep ----------------
// wbf[256][2304] bf16, j = k*256+c  <- adapt_w[o][c*9+k]
// lsw[16][2304]  bf16, rows 0..2 = loc_w, shape_w0, shape_w1; rows 3..15 zero
__global__ void __launch_bounds__(256) wconv_kernel(
    const float* __restrict__ loc_w, const float* __restrict__ shape_w,
    const float* __restrict__ adw,
    short* __restrict__ wbf, short* __restrict__ lsw)
{
    int i = blockIdx.x * 256 + threadIdx.x;
    if (i < 256 * CK) {
        int o = i / CK, j = i % CK;
        int k = j >> 8, c = j & 255;
        wbf[i] = f2bf(adw[o * CK + c * 9 + k]);
    } else {
        int i2 = i - 256 * CK;          // < 16*2304
        int o = i2 / CK, j = i2 % CK;
        int k = j >> 8, c = j & 255;
        float v = 0.f;
        if (o == 0)      v = loc_w[c * 9 + k];
        else if (o == 1) v = shape_w[c * 9 + k];
        else if (o == 2) v = shape_w[CK + c * 9 + k];
        lsw[i2] = f2bf(v);
    }
}

// ---------------- Kernel 1: NCHW fp32 -> NHWC fp16 transpose ----------------
__global__ void __launch_bounds__(256) transpose_kernel(
    const float* __restrict__ f0, const float* __restrict__ f1,
    const float* __restrict__ f2, const float* __restrict__ f3,
    _Float16* __restrict__ ft)
{
    __shared__ float lds[64][65];
    int bid = blockIdx.x, tid = threadIdx.x;
    int lvl = (bid < 1904) ? 0 : (bid < 2384) ? 1 : (bid < 2504) ? 2 : 3;
    int base = (lvl == 0) ? 0 : (lvl == 1) ? 1904 : (lvl == 2) ? 2384 : 2504;
    int nbhw = (lvl == 0) ? 238 : (lvl == 1) ? 60 : (lvl == 2) ? 15 : 4;
    const float* f = (lvl == 0) ? f0 : (lvl == 1) ? f1 : (lvl == 2) ? f2 : f3;
    int HW = cHW[lvl];
    int b = bid - base;
    int bh = b % nbhw;
    int cg = (b / nbhw) & 3;
    int n  = b / (nbhw * 4);
    int hw0 = bh * 64;

    int pxl = tid & 63, cl = tid >> 6;
    int hwr = hw0 + pxl;
    if (hwr < HW) {
        #pragma unroll
        for (int r = 0; r < 16; ++r) {
            int c = r * 4 + cl;
            lds[c][pxl] = f[(long)(n * 256 + cg * 64 + c) * HW + hwr];
        }
    }
    __syncthreads();
    int px2 = tid >> 2, q = tid & 3;
    int hww = hw0 + px2;
    if (hww < HW) {
        _Float16* dst = ft + (long)cFTO[lvl] + ((long)(n * HW + hww) << 8) + cg * 64 + q * 16;
        #pragma unroll
        for (int j = 0; j < 16; j += 4) {
            h16x4 v;
            v[0] = (_Float16)lds[q * 16 + j + 0][px2];
            v[1] = (_Float16)lds[q * 16 + j + 1][px2];
            v[2] = (_Float16)lds[q * 16 + j + 2][px2];
            v[3] = (_Float16)lds[q * 16 + j + 3][px2];
            *(h16x4*)(dst + j) = v;
        }
    }
}

// ---------------- Kernel 2: fused locshape + deform (all levels) ----------------
// 512 thr. Phase A: plain im2col -> val. Phase B: 16x2304 MFMA -> loc/sh/ref + shm.
// Phase C: deformed im2col -> val. Phase D: 256x2304 GEMM -> ad out.
__global__ void __launch_bounds__(512, 1) fused_kernel(
    const _Float16* __restrict__ ft,
    const float* __restrict__ offw,
    const short* __restrict__ wbf,
    const short* __restrict__ lsw,
    const float* __restrict__ loc_b, const float* __restrict__ shape_b,
    float* __restrict__ out)
{
    __shared__ short val[TP][PADK];       // 148,480 B
    __shared__ float shm[TP][2];
    __shared__ float offsm[288];

    int bid = blockIdx.x, tid = threadIdx.x;
    int lvl  = (bid < 950) ? 0 : (bid < 1188) ? 1 : (bid < 1248) ? 2 : 3;
    int base = (lvl == 0) ? 0 : (lvl == 1) ? 950 : (lvl == 2) ? 1188 : 1248;
    int H = cH[lvl], W = cW[lvl], HW = cHW[lvl];
    int total = 2 * HW;
    int pix0 = (bid - base) * TP;
    const _Float16* ftl = ft + (long)cFTO[lvl];
    int wv = tid >> 6, lane = tid & 63;
    int nn = lane & 15, c8 = lane >> 4;

    if (tid < 288) offsm[tid] = offw[tid];

    // ---- Phase A: plain masked im2col (item = (px,k), 64 lanes x 4ch) ----
    for (int item = wv; item < TP * 9; item += 8) {
        int p = item / 9, k = item % 9;
        int pix = pix0 + p;
        int c4 = lane * 4;
        s16x4 pk = {0, 0, 0, 0};
        if (pix < total) {
            int n = pix / HW, rem = pix - n * HW;
            int h = rem / W, w = rem - h * W;
            int ky = k / 3, kx = k - ky * 3;
            int y = h - 1 + ky, x = w - 1 + kx;
            if ((unsigned)y < (unsigned)H && (unsigned)x < (unsigned)W) {
                h16x4 hv = *(const h16x4*)(ftl + ((long)(n * HW + y * W + x) << 8) + c4);
                pk[0] = f2bf((float)hv[0]); pk[1] = f2bf((float)hv[1]);
                pk[2] = f2bf((float)hv[2]); pk[3] = f2bf((float)hv[3]);
            }
        }
        *(s16x4*)&val[p][k * 256 + c4] = pk;
    }
    __syncthreads();

    // ---- Phase B: locshape MFMA (waves 0,1; wave wv -> px wv*16+nn) ----
    if (wv < 2) {
        f32x4 acc = {0.f, 0.f, 0.f, 0.f};
        const short* ar = lsw + nn * CK + c8 * 8;
        const short* br = &val[wv * 16 + nn][c8 * 8];
        for (int k0 = 0; k0 < CK; k0 += 32) {
            bf16x8 a = *(const bf16x8*)(ar + k0);
            bf16x8 b = *(const bf16x8*)(br + k0);
            acc = __builtin_amdgcn_mfma_f32_16x16x32_bf16(a, b, acc, 0, 0, 0);
        }
        int p = wv * 16 + nn;
        int pix = pix0 + p;
        if (pix < total && c8 == 0) {
            float a0 = acc[0] + loc_b[0];
            float a1 = acc[1] + shape_b[0];
            float a2 = acc[2] + shape_b[1];
            int n = pix / HW, rem = pix - n * HW;
            out[cLOC[lvl] + n * HW + rem] = 1.f / (1.f + expf(-a0));
            out[cSH[lvl]  + (n * 2 + 0) * HW + rem] = a1;
            out[cSH[lvl]  + (n * 2 + 1) * HW + rem] = a2;
            out[cREF[lvl] + (n * 2 + 0) * HW + rem] = cSS[lvl] * expf(a1);
            out[cREF[lvl] + (n * 2 + 1) * HW + rem] = cSS[lvl] * expf(a2);
            shm[p][0] = a1;
            shm[p][1] = a2;
        }
    }
    __syncthreads();

    // ---- Phase C: deformed bilinear im2col (item = (px,k), lane g = lane>>4) ----
    for (int item = wv; item < TP * 9; item += 8) {
        int p = item / 9, k = item % 9;
        int pix = pix0 + p;
        int c4 = lane * 4;
        int g = lane >> 4;
        int gk = g * 9 + k;
        s16x4 pk = {0, 0, 0, 0};
        if (pix < total) {
            int n = pix / HW, rem = pix - n * HW;
            int h = rem / W, w = rem - h * W;
            float s0 = shm[p][0], s1 = shm[p][1];
            float dy = offsm[gk * 4 + 0] * s0 + offsm[gk * 4 + 1] * s1;
            float dx = offsm[gk * 4 + 2] * s0 + offsm[gk * 4 + 3] * s1;
            int ky = k / 3, kx = k - ky * 3;
            float py = (float)(h - 1 + ky) + dy;
            float px = (float)(w - 1 + kx) + dx;
            float fy = floorf(py), fx = floorf(px);
            float ly = py - fy, lx = px - fx;
            int y0 = (int)fy, x0 = (int)fx;
            int y1 = y0 + 1, x1 = x0 + 1;
            float w00 = (1.f - ly) * (1.f - lx);
            float w01 = (1.f - ly) * lx;
            float w10 = ly * (1.f - lx);
            float w11 = ly * lx;
            float m00 = ((unsigned)y0 < (unsigned)H && (unsigned)x0 < (unsigned)W) ? w00 : 0.f;
            float m01 = ((unsigned)y0 < (unsigned)H && (unsigned)x1 < (unsigned)W) ? w01 : 0.f;
            float m10 = ((unsigned)y1 < (unsigned)H && (unsigned)x0 < (unsigned)W) ? w10 : 0.f;
            float m11 = ((unsigned)y1 < (unsigned)H && (unsigned)x1 < (unsigned)W) ? w11 : 0.f;
            int cy0 = min(max(y0, 0), H - 1), cy1 = min(max(y1, 0), H - 1);
            int cx0 = min(max(x0, 0), W - 1), cx1 = min(max(x1, 0), W - 1);
            long nb = (long)n * HW;
            h16x4 v00 = *(const h16x4*)(ftl + ((nb + cy0 * W + cx0) << 8) + c4);
            h16x4 v01 = *(const h16x4*)(ftl + ((nb + cy0 * W + cx1) << 8) + c4);
            h16x4 v10 = *(const h16x4*)(ftl + ((nb + cy1 * W + cx0) << 8) + c4);
            h16x4 v11 = *(const h16x4*)(ftl + ((nb + cy1 * W + cx1) << 8) + c4);
            #pragma unroll
            for (int j = 0; j < 4; ++j) {
                float v = fmaf(m00, (float)v00[j],
                          fmaf(m01, (float)v01[j],
                          fmaf(m10, (float)v10[j], m11 * (float)v11[j])));
                pk[j] = f2bf(v);
            }
        }
        *(s16x4*)&val[p][k * 256 + c4] = pk;
    }
    __syncthreads();

    // ---- Phase D: GEMM 256oc x 32px: wave wv -> oc rows wv*32..+31 ----
    f32x4 a00 = {0,0,0,0}, a01 = {0,0,0,0}, a10 = {0,0,0,0}, a11 = {0,0,0,0};
    const short* wp  = wbf + (wv * 32 + nn) * CK + c8 * 8;
    const short* b0p = &val[nn][c8 * 8];
    const short* b1p = &val[16 + nn][c8 * 8];
    #pragma unroll 2
    for (int k0 = 0; k0 < CK; k0 += 32) {
        bf16x8 b0 = *(const bf16x8*)(b0p + k0);
        bf16x8 b1 = *(const bf16x8*)(b1p + k0);
        bf16x8 w0 = *(const bf16x8*)(wp + k0);
        bf16x8 w1 = *(const bf16x8*)(wp + 16 * CK + k0);
        a00 = __builtin_amdgcn_mfma_f32_16x16x32_bf16(w0, b0, a00, 0, 0, 0);
        a01 = __builtin_amdgcn_mfma_f32_16x16x32_bf16(w0, b1, a01, 0, 0, 0);
        a10 = __builtin_amdgcn_mfma_f32_16x16x32_bf16(w1, b0, a10, 0, 0, 0);
        a11 = __builtin_amdgcn_mfma_f32_16x16x32_bf16(w1, b1, a11, 0, 0, 0);
    }
    #pragma unroll
    for (int nh = 0; nh < 2; ++nh) {
        int pix = pix0 + nh * 16 + nn;
        if (pix >= total) continue;
        int n = pix / HW, rem = pix - n * HW;
        long ob = (long)cAD[lvl] + ((long)n << 8) * HW + rem;
        f32x4 accA = nh ? a01 : a00;
        f32x4 accB = nh ? a11 : a10;
        #pragma unroll
        for (int r = 0; r < 4; ++r) {
            int oc0 = wv * 32 + c8 * 4 + r;
            float v0 = accA[r];
            float v1 = accB[r];
            out[ob + (long)oc0 * HW]        = v0 > 0.f ? v0 : 0.f;
            out[ob + (long)(oc0 + 16) * HW] = v1 > 0.f ? v1 : 0.f;
        }
    }
}

extern "C" void kernel_launch(void* const* d_in, const int* in_sizes, int n_in,
                              void* d_out, int out_size, void* d_ws, size_t ws_size,
                              hipStream_t stream)
{
    const float* f0 = (const float*)d_in[0];
    const float* f1 = (const float*)d_in[1];
    const float* f2 = (const float*)d_in[2];
    const float* f3 = (const float*)d_in[3];
    const float* loc_w    = (const float*)d_in[4];
    const float* loc_b    = (const float*)d_in[5];
    const float* shape_w  = (const float*)d_in[6];
    const float* shape_b  = (const float*)d_in[7];
    const float* offset_w = (const float*)d_in[8];
    const float* adapt_w  = (const float*)d_in[9];
    float* out = (float*)d_out;

    short* wbf = (short*)d_ws;                         // 256*2304 shorts
    short* lsw = wbf + 256 * CK;                       // 16*2304 shorts
    _Float16* ft = (_Float16*)((char*)d_ws + 1253376); // 10,340,864 halfs (20.7 MB)

    wconv_kernel<<<2448, 256, 0, stream>>>(loc_w, shape_w, adapt_w, wbf, lsw);
    transpose_kernel<<<2536, 256, 0, stream>>>(f0, f1, f2, f3, ft);
    fused_kernel<<<1264, 512, 0, stream>>>(ft, offset_w, wbf, lsw, loc_b, shape_b, out);
}

// Round 4
// 251.521 us; speedup vs baseline: 49.8074x; 1.6585x over previous
//
#include <hip/hip_runtime.h>
#include <hip/hip_bf16.h>
#include <cmath>

typedef _Float16 h16x4 __attribute__((ext_vector_type(4)));
typedef _Float16 h16x8 __attribute__((ext_vector_type(8)));
typedef float    f32x4  __attribute__((ext_vector_type(4)));
typedef float    f32x16 __attribute__((ext_vector_type(16)));

#define CK 2304
#define KHALF 1152
#define PADH 1160          // val row pitch in halves (2320 B)
#define TP 64              // pixels per fused block

// ---- compile-time level tables ----
constexpr int  eH[4]   = {100, 50, 25, 13};
constexpr int  eW[4]   = {152, 76, 38, 19};
constexpr long eFTO[4] = {0, 7782400, 9728000, 10214400};
constexpr long eLOC[4] = {0, 30400, 38000, 39900};
constexpr long eSH[4]  = {40394, 101194, 116394, 120194};
constexpr long eREF[4] = {121182, 181982, 197182, 200982};
constexpr long eAD[4]  = {201970, 7984370, 9929970, 10416370};
constexpr float eSS[4] = {64.f, 128.f, 256.f, 512.f};

// transpose kernel per-level constants (runtime constant mem, cheap)
__device__ __constant__ int cHW[4]  = {15200, 3800, 950, 247};
__device__ __constant__ long cFTO[4] = {0, 7782400, 9728000, 10214400};

static __device__ __forceinline__ h16x4 hsplat(float m) {
    _Float16 t = (_Float16)m;
    return (h16x4){t, t, t, t};
}

// ---------------- Kernel 0: weight prep (fp16) ----------------
// wbf2[kh][256][1152], j' = k*128 + (c - kh*128)   <- adapt_w[o][c*9+k]
// lsw [16][2304], j = k*256 + c ; rows 0..2 = loc_w, shape_w0, shape_w1
__global__ void __launch_bounds__(256) wconv_kernel(
    const float* __restrict__ loc_w, const float* __restrict__ shape_w,
    const float* __restrict__ adw,
    _Float16* __restrict__ wbf2, _Float16* __restrict__ lsw)
{
    int i = blockIdx.x * 256 + threadIdx.x;
    if (i < 589824) {
        int kh = i / 294912;
        int r  = i - kh * 294912;
        int o  = r / 1152;
        int j  = r - o * 1152;
        int k  = j >> 7;
        int c  = kh * 128 + (j & 127);
        wbf2[i] = (_Float16)adw[o * CK + c * 9 + k];
    } else {
        int i2 = i - 589824;               // < 36864
        int o = i2 / CK;
        int j = i2 - o * CK;
        int k = j >> 8, c = j & 255;
        float v = 0.f;
        if (o == 0)      v = loc_w[c * 9 + k];
        else if (o == 1) v = shape_w[c * 9 + k];
        else if (o == 2) v = shape_w[CK + c * 9 + k];
        lsw[i2] = (_Float16)v;
    }
}

// ---------------- Kernel 1: NCHW fp32 -> NHWC fp16 transpose ----------------
__global__ void __launch_bounds__(256) transpose_kernel(
    const float* __restrict__ f0, const float* __restrict__ f1,
    const float* __restrict__ f2, const float* __restrict__ f3,
    _Float16* __restrict__ ft)
{
    __shared__ float lds[64][65];
    int bid = blockIdx.x, tid = threadIdx.x;
    int lvl = (bid < 1904) ? 0 : (bid < 2384) ? 1 : (bid < 2504) ? 2 : 3;
    int base = (lvl == 0) ? 0 : (lvl == 1) ? 1904 : (lvl == 2) ? 2384 : 2504;
    int nbhw = (lvl == 0) ? 238 : (lvl == 1) ? 60 : (lvl == 2) ? 15 : 4;
    const float* f = (lvl == 0) ? f0 : (lvl == 1) ? f1 : (lvl == 2) ? f2 : f3;
    int HW = cHW[lvl];
    int b = bid - base;
    int bh = b % nbhw;
    int cg = (b / nbhw) & 3;
    int n  = b / (nbhw * 4);
    int hw0 = bh * 64;

    int pxl = tid & 63, cl = tid >> 6;
    int hwr = hw0 + pxl;
    if (hwr < HW) {
        #pragma unroll
        for (int r = 0; r < 16; ++r) {
            int c = r * 4 + cl;
            lds[c][pxl] = f[(long)(n * 256 + cg * 64 + c) * HW + hwr];
        }
    }
    __syncthreads();
    int px2 = tid >> 2, q = tid & 3;
    int hww = hw0 + px2;
    if (hww < HW) {
        _Float16* dst = ft + cFTO[lvl] + ((long)(n * HW + hww) << 8) + cg * 64 + q * 16;
        #pragma unroll
        for (int j = 0; j < 16; j += 4) {
            h16x4 v;
            v[0] = (_Float16)lds[q * 16 + j + 0][px2];
            v[1] = (_Float16)lds[q * 16 + j + 1][px2];
            v[2] = (_Float16)lds[q * 16 + j + 2][px2];
            v[3] = (_Float16)lds[q * 16 + j + 3][px2];
            *(h16x4*)(dst + j) = v;
        }
    }
}

// ---------------- fused body (templated per level) ----------------
template<int LVL>
static __device__ __forceinline__ void fused_body(
    int bidl,
    _Float16 (*val)[PADH], float (*redB)[3][4], float* offsm, float (*shm)[2],
    int* pxh, int* pxw, int* pxn,
    const _Float16* __restrict__ ft,
    const float* __restrict__ offw,
    const _Float16* __restrict__ wbf2,
    const _Float16* __restrict__ lsw,
    const float* __restrict__ loc_b, const float* __restrict__ shape_b,
    float* __restrict__ out)
{
    constexpr int H = eH[LVL], W = eW[LVL];
    constexpr int HW = H * W;
    constexpr int total = 2 * HW;
    const _Float16* ftl = ft + eFTO[LVL];
    float* loc_o = out + eLOC[LVL];
    float* sh_o  = out + eSH[LVL];
    float* ref_o = out + eREF[LVL];
    float* ad_o  = out + eAD[LVL];

    int tid = threadIdx.x;
    int wv = tid >> 6, lane = tid & 63;
    int nn = lane & 15, c8 = lane >> 4;
    int pix0 = bidl * TP;

    // ---- pre: pixel meta + offsets ----
    if (tid < TP) {
        int pix = pix0 + tid;
        if (pix < total) {
            int n = pix / HW;            // compile-time divisor
            int rem = pix - n * HW;
            int hh = rem / W;
            pxn[tid] = n; pxh[tid] = hh; pxw[tid] = rem - hh * W;
        } else { pxn[tid] = -1; pxh[tid] = 0; pxw[tid] = 0; }
    }
    if (tid < 288) offsm[tid] = offw[tid];
    __syncthreads();

    // ---- Phase B: locshape GEMM, B-frags direct from global ft ----
    {
        int pxt = wv & 3, kq = wv >> 2;       // 4 px-tiles x 4 k-quarters
        int p = pxt * 16 + nn;
        int n = pxn[p], hh = pxh[p], ww = pxw[p];
        f32x4 acc = {0.f, 0.f, 0.f, 0.f};
        const _Float16* ar = lsw + nn * CK + kq * 576 + c8 * 8;
        #pragma unroll 6
        for (int s = 0; s < 18; ++s) {
            int j0 = kq * 576 + s * 32;
            int k = j0 >> 8;
            int c = (j0 & 255) + c8 * 8;
            int ky = (k * 171) >> 9;
            int kx = k - ky * 3;
            int y = hh - 1 + ky, x = ww - 1 + kx;
            h16x8 b = {0,0,0,0,0,0,0,0};
            if (n >= 0 && (unsigned)y < (unsigned)H && (unsigned)x < (unsigned)W)
                b = *(const h16x8*)(ftl + ((long)(n * HW + y * W + x) << 8) + c);
            h16x8 a = *(const h16x8*)(ar + s * 32);
            acc = __builtin_amdgcn_mfma_f32_16x16x32_f16(a, b, acc, 0, 0, 0);
        }
        if (c8 == 0) {
            #pragma unroll
            for (int r = 0; r < 3; ++r) redB[p][r][kq] = acc[r];
        }
    }
    __syncthreads();
    if (tid < 192) {
        int p = tid & 63, r = tid >> 6;
        float s = redB[p][r][0] + redB[p][r][1] + redB[p][r][2] + redB[p][r][3];
        int pix = pix0 + p;
        if (pix < total) {
            int n = pxn[p];
            long sp = (long)pxh[p] * W + pxw[p];
            if (r == 0) {
                s += loc_b[0];
                loc_o[n * HW + sp] = 1.f / (1.f + expf(-s));
            } else {
                s += shape_b[r - 1];
                sh_o[(n * 2 + r - 1) * HW + sp] = s;
                ref_o[(n * 2 + r - 1) * HW + sp] = eSS[LVL] * expf(s);
                shm[p][r - 1] = s;
            }
        }
    }
    __syncthreads();

    // ---- Phases C/D per K-half ----
    int mt = wv >> 1, kg = wv & 1;
    int col = lane & 31, khalf = lane >> 5;
    f32x16 accT0 = {0,0,0,0,0,0,0,0,0,0,0,0,0,0,0,0};
    f32x16 accT1 = {0,0,0,0,0,0,0,0,0,0,0,0,0,0,0,0};

    for (int kh = 0; kh < 2; ++kh) {
        // ---- Phase C: deformed bilinear im2col, half-K (128 ch) ----
        {
            int li = lane & 31;
            int sub = lane >> 5;
            int c4 = li * 4;
            int g = kh * 2 + (li >> 4);
            int choff = kh * 128 + c4;
            #pragma unroll 2
            for (int i = 0; i < 18; ++i) {
                int e = (i * 16 + wv) * 2 + sub;     // < 576
                int p = e / 9;
                int k = e - p * 9;
                int n = pxn[p];
                h16x4 r4 = {0, 0, 0, 0};
                if (n >= 0) {
                    float s0 = shm[p][0], s1 = shm[p][1];
                    int gk4 = (g * 9 + k) * 4;
                    float dy = offsm[gk4 + 0] * s0 + offsm[gk4 + 1] * s1;
                    float dx = offsm[gk4 + 2] * s0 + offsm[gk4 + 3] * s1;
                    int ky = (k * 171) >> 9;
                    int kx = k - ky * 3;
                    float py  = (float)(pxh[p] - 1 + ky) + dy;
                    float pxf = (float)(pxw[p] - 1 + kx) + dx;
                    float fy = floorf(py), fx = floorf(pxf);
                    float ly = py - fy, lx = pxf - fx;
                    int y0 = (int)fy, x0 = (int)fx;
                    int y1 = y0 + 1, x1 = x0 + 1;
                    float w00 = (1.f - ly) * (1.f - lx);
                    float w01 = (1.f - ly) * lx;
                    float w10 = ly * (1.f - lx);
                    float w11 = ly * lx;
                    bool by0 = (unsigned)y0 < (unsigned)H, by1 = (unsigned)y1 < (unsigned)H;
                    bool bx0 = (unsigned)x0 < (unsigned)W, bx1 = (unsigned)x1 < (unsigned)W;
                    float m00 = (by0 && bx0) ? w00 : 0.f;
                    float m01 = (by0 && bx1) ? w01 : 0.f;
                    float m10 = (by1 && bx0) ? w10 : 0.f;
                    float m11 = (by1 && bx1) ? w11 : 0.f;
                    int cy0 = min(max(y0, 0), H - 1), cy1 = min(max(y1, 0), H - 1);
                    int cx0 = min(max(x0, 0), W - 1), cx1 = min(max(x1, 0), W - 1);
                    const _Float16* fb = ftl + ((long)(n * HW) << 8) + choff;
                    h16x4 v00 = *(const h16x4*)(fb + ((long)(cy0 * W + cx0) << 8));
                    h16x4 v01 = *(const h16x4*)(fb + ((long)(cy0 * W + cx1) << 8));
                    h16x4 v10 = *(const h16x4*)(fb + ((long)(cy1 * W + cx0) << 8));
                    h16x4 v11 = *(const h16x4*)(fb + ((long)(cy1 * W + cx1) << 8));
                    r4 = v00 * hsplat(m00) + v01 * hsplat(m01)
                       + v10 * hsplat(m10) + v11 * hsplat(m11);
                }
                *(h16x4*)&val[p][k * 128 + c4] = r4;
            }
        }
        __syncthreads();

        // ---- Phase D: GEMM (32x32x16 f16), wave = oc-tile mt x K-group kg ----
        {
            const _Float16* wp  = wbf2 + (long)kh * 294912
                                + (long)(mt * 32 + col) * KHALF + kg * 576 + khalf * 8;
            const _Float16* bp0 = &val[col][kg * 576 + khalf * 8];
            const _Float16* bp1 = &val[32 + col][kg * 576 + khalf * 8];
            #pragma unroll 6
            for (int s = 0; s < 36; ++s) {
                h16x8 wf = *(const h16x8*)(wp  + s * 16);
                h16x8 b0 = *(const h16x8*)(bp0 + s * 16);
                h16x8 b1 = *(const h16x8*)(bp1 + s * 16);
                accT0 = __builtin_amdgcn_mfma_f32_32x32x16_f16(wf, b0, accT0, 0, 0, 0);
                accT1 = __builtin_amdgcn_mfma_f32_32x32x16_f16(wf, b1, accT1, 0, 0, 0);
            }
        }
        __syncthreads();
    }

    // ---- cross-kg reduce (part aliases dead val) + epilogue ----
    float* part = (float*)&val[0][0];
    if (kg == 1) {
        int tb0 = ((mt * 2 + 0) * 64 + lane) * 18;
        int tb1 = ((mt * 2 + 1) * 64 + lane) * 18;
        #pragma unroll
        for (int q = 0; q < 16; q += 2) {
            *(float2*)&part[tb0 + q] = make_float2(accT0[q], accT0[q + 1]);
            *(float2*)&part[tb1 + q] = make_float2(accT1[q], accT1[q + 1]);
        }
    }
    __syncthreads();
    if (kg == 0) {
        int tb0 = ((mt * 2 + 0) * 64 + lane) * 18;
        int tb1 = ((mt * 2 + 1) * 64 + lane) * 18;
        #pragma unroll
        for (int q = 0; q < 16; ++q) {
            accT0[q] += part[tb0 + q];
            accT1[q] += part[tb1 + q];
        }
        #pragma unroll
        for (int t = 0; t < 2; ++t) {
            int p = t * 32 + col;
            int n = pxn[p];
            if (n < 0) continue;
            long sp = (long)pxh[p] * W + pxw[p];
            float* ob = ad_o + ((long)n * 256 + mt * 32) * HW + sp;
            #pragma unroll
            for (int reg = 0; reg < 16; ++reg) {
                int row = (reg & 3) + 8 * (reg >> 2) + 4 * khalf;
                float v = t ? accT1[reg] : accT0[reg];
                ob[(long)row * HW] = v > 0.f ? v : 0.f;
            }
        }
    }
}

__global__ void __launch_bounds__(1024, 4) fused_kernel(
    const _Float16* __restrict__ ft,
    const float* __restrict__ offw,
    const _Float16* __restrict__ wbf2,
    const _Float16* __restrict__ lsw,
    const float* __restrict__ loc_b, const float* __restrict__ shape_b,
    float* __restrict__ out)
{
    __shared__ _Float16 val[TP][PADH];     // 148,480 B
    __shared__ float redB[TP][3][4];       // 3,072 B
    __shared__ float offsm[288];
    __shared__ float shm[TP][2];
    __shared__ int pxh[TP], pxw[TP], pxn[TP];

    int bid = blockIdx.x;
    if (bid < 475)
        fused_body<0>(bid,       val, redB, offsm, shm, pxh, pxw, pxn, ft, offw, wbf2, lsw, loc_b, shape_b, out);
    else if (bid < 594)
        fused_body<1>(bid - 475, val, redB, offsm, shm, pxh, pxw, pxn, ft, offw, wbf2, lsw, loc_b, shape_b, out);
    else if (bid < 624)
        fused_body<2>(bid - 594, val, redB, offsm, shm, pxh, pxw, pxn, ft, offw, wbf2, lsw, loc_b, shape_b, out);
    else
        fused_body<3>(bid - 624, val, redB, offsm, shm, pxh, pxw, pxn, ft, offw, wbf2, lsw, loc_b, shape_b, out);
}

extern "C" void kernel_launch(void* const* d_in, const int* in_sizes, int n_in,
                              void* d_out, int out_size, void* d_ws, size_t ws_size,
                              hipStream_t stream)
{
    const float* f0 = (const float*)d_in[0];
    const float* f1 = (const float*)d_in[1];
    const float* f2 = (const float*)d_in[2];
    const float* f3 = (const float*)d_in[3];
    const float* loc_w    = (const float*)d_in[4];
    const float* loc_b    = (const float*)d_in[5];
    const float* shape_w  = (const float*)d_in[6];
    const float* shape_b  = (const float*)d_in[7];
    const float* offset_w = (const float*)d_in[8];
    const float* adapt_w  = (const float*)d_in[9];
    float* out = (float*)d_out;

    _Float16* wbf2 = (_Float16*)d_ws;          // 589,824 halves
    _Float16* lsw  = wbf2 + 589824;            // 36,864 halves
    _Float16* ft   = wbf2 + 626688;            // 10,340,864 halves

    wconv_kernel<<<2448, 256, 0, stream>>>(loc_w, shape_w, adapt_w, wbf2, lsw);
    transpose_kernel<<<2536, 256, 0, stream>>>(f0, f1, f2, f3, ft);
    fused_kernel<<<632, 1024, 0, stream>>>(ft, offset_w, wbf2, lsw, loc_b, shape_b, out);
}